// Round 11
// baseline (299.446 us; speedup 1.0000x reference)
//
#include <hip/hip_runtime.h>

typedef _Float16 h2 __attribute__((ext_vector_type(2)));

__device__ __forceinline__ h2 h2splat(float s) {
    const _Float16 v = (_Float16)s;
    h2 r; r.x = v; r.y = v; return r;
}
__device__ __forceinline__ h2 h2fma(h2 a, h2 b, h2 c) { return __builtin_elementwise_fma(a, b, c); }
__device__ __forceinline__ h2 h2relu(h2 a) {
    h2 z; z.x = (_Float16)0.0f; z.y = (_Float16)0.0f;
    return __builtin_elementwise_max(a, z);
}

// ---- ws layout ----
// h2-duplicated weights (one dword each), index o*22 + k  (o = 0..23):
//   k=0..5  sym (cols 0,4,6, (1+2)/2, (3+5)/2, (7+8)/2); k=6..8 anti; k=9 b1
//   (j-MLP at +0, n-MLP at +10); k=20 w2j; k=21 w2n
// floats at Wf = ws+528:
//   [r*6+c] Qn[r][c] = -Minv[r][3+c];  [54] b2j;  [55] 2*b2n

__global__ __launch_bounds__(256) void prep_kernel(
    const float* __restrict__ j_w1, const float* __restrict__ j_b1,
    const float* __restrict__ j_w2, const float* __restrict__ j_b2,
    const float* __restrict__ n_w1, const float* __restrict__ n_b1,
    const float* __restrict__ n_w2, const float* __restrict__ n_b2,
    const float* __restrict__ Mg, const float* __restrict__ Minvg,
    float* __restrict__ ws)
{
    const int t = threadIdx.x;
    h2* wh = reinterpret_cast<h2*>(ws);
    if (t < 48) {
        const int o = t >> 1, which = t & 1;
        const float* w1 = which ? n_w1 : j_w1;
        const float* b1 = which ? n_b1 : j_b1;
        float w[9];
        #pragma unroll
        for (int i = 0; i < 9; ++i) w[i] = w1[o * 9 + i];
        const int b = o * 22 + which * 10;
        wh[b + 0] = h2splat(w[0]);
        wh[b + 1] = h2splat(w[4]);
        wh[b + 2] = h2splat(w[6]);
        wh[b + 3] = h2splat(0.5f * (w[1] + w[2]));
        wh[b + 4] = h2splat(0.5f * (w[3] + w[5]));
        wh[b + 5] = h2splat(0.5f * (w[7] + w[8]));
        wh[b + 6] = h2splat(0.5f * (w[1] - w[2]));
        wh[b + 7] = h2splat(0.5f * (w[3] - w[5]));
        wh[b + 8] = h2splat(0.5f * (w[7] - w[8]));
        wh[b + 9] = h2splat(b1[o]);
        if (!which) {
            wh[o * 22 + 20] = h2splat(j_w2[o]);
            wh[o * 22 + 21] = h2splat(n_w2[o]);
        }
    } else if (t >= 64 && t < 64 + 54) {
        const int e = t - 64, r = e / 6, c = e % 6;
        ws[528 + e] = -Minvg[r * 9 + 3 + c];
    } else if (t == 254) {
        ws[528 + 54] = j_b2[0];
    } else if (t == 255) {
        ws[528 + 55] = 2.0f * n_b2[0];
    }
}

__device__ __forceinline__ void process_tile(
    const float4* __restrict__ cur, const h2* __restrict__ Wh,
    const float* __restrict__ Wf, float* __restrict__ out,
    long base, int n2)
{
    float fv[9][4];
    #pragma unroll
    for (int i = 0; i < 9; ++i) {
        fv[i][0] = cur[i].x; fv[i][1] = cur[i].y;
        fv[i][2] = cur[i].z; fv[i][3] = cur[i].w;
    }

    // ---- phase 1 (f32, sparse TM butterfly): tv = TM @ f ----
    float tv[9][4];
    #pragma unroll
    for (int k = 0; k < 4; ++k) {
        const float f0 = fv[0][k], f1 = fv[1][k], f2 = fv[2][k], f3 = fv[3][k];
        const float f4 = fv[4][k], f5 = fv[5][k], f6 = fv[6][k], f7 = fv[7][k], f8 = fv[8][k];
        const float P = f1 + f2, Q = f3 + f4, R = f5 + f7, S = f6 + f8;
        const float D = f5 - f7, F = f6 - f8, G = f1 - f2, H = f3 - f4;
        const float A = P + Q, B = R + S;
        const float C = P - Q, K = G - H;
        tv[0][k] = f0 + A + B;                               // rho
        tv[1][k] = R - S;                                    // m4 (xy)
        tv[2][k] = fmaf(4.0f, B, fmaf(-2.0f, A, f0));        // m6 (g)
        tv[3][k] = fmaf(2.0f, D, C);                         // m1+m2
        tv[4][k] = 0.33333334f * fmaf(4.0f, B, fmaf(-2.0f, f0, A)); // m3+m5
        tv[5][k] = fmaf(8.0f, D, -2.0f * C);                 // m7+m8
        tv[6][k] = fmaf(-2.0f, F, K);                        // m1-m2
        tv[7][k] = G + H;                                    // m3-m5
        tv[8][k] = fmaf(-8.0f, F, -2.0f * K);                // m7-m8
    }

    // ---- f16 copy for the MLP (2 points per h2) ----
    h2 tvh[9][2];
    #pragma unroll
    for (int r = 0; r < 9; ++r) {
        tvh[r][0].x = (_Float16)tv[r][0]; tvh[r][0].y = (_Float16)tv[r][1];
        tvh[r][1].x = (_Float16)tv[r][2]; tvh[r][1].y = (_Float16)tv[r][3];
    }

    // ---- phase 2 (packed f16): fused hidden layer ----
    h2 accj[2], accjf[2], accn[2];
    #pragma unroll
    for (int p = 0; p < 2; ++p) { accj[p] = h2splat(0.f); accjf[p] = h2splat(0.f); accn[p] = h2splat(0.f); }

    #pragma unroll 4
    for (int o = 0; o < 24; ++o) {
        const h2 s0 = Wh[o*22+0], s1 = Wh[o*22+1], s2 = Wh[o*22+2];
        const h2 s3 = Wh[o*22+3], s4 = Wh[o*22+4], s5 = Wh[o*22+5];
        const h2 a0 = Wh[o*22+6], a1 = Wh[o*22+7], a2 = Wh[o*22+8];
        const h2 b1j = Wh[o*22+9];
        const h2 u0 = Wh[o*22+10], u1 = Wh[o*22+11], u2 = Wh[o*22+12];
        const h2 u3 = Wh[o*22+13], u4 = Wh[o*22+14], u5 = Wh[o*22+15];
        const h2 v0 = Wh[o*22+16], v1 = Wh[o*22+17], v2 = Wh[o*22+18];
        const h2 b1n = Wh[o*22+19];
        const h2 w2j = Wh[o*22+20], w2n = Wh[o*22+21];
        #pragma unroll
        for (int p = 0; p < 2; ++p) {
            h2 s = h2fma(s0, tvh[0][p], b1j);
            s = h2fma(s1, tvh[1][p], s);
            s = h2fma(s2, tvh[2][p], s);
            s = h2fma(s3, tvh[3][p], s);
            s = h2fma(s4, tvh[4][p], s);
            s = h2fma(s5, tvh[5][p], s);
            h2 a = a0 * tvh[6][p];
            a = h2fma(a1, tvh[7][p], a);
            a = h2fma(a2, tvh[8][p], a);
            const h2 hs = h2relu(s + a);
            const h2 hd = h2relu(s - a);
            accj[p]  = h2fma(w2j, hs, accj[p]);
            accjf[p] = h2fma(w2j, hd, accjf[p]);

            h2 sn = h2fma(u0, tvh[0][p], b1n);
            sn = h2fma(u1, tvh[1][p], sn);
            sn = h2fma(u2, tvh[2][p], sn);
            sn = h2fma(u3, tvh[3][p], sn);
            sn = h2fma(u4, tvh[4][p], sn);
            sn = h2fma(u5, tvh[5][p], sn);
            h2 an = v0 * tvh[6][p];
            an = h2fma(v1, tvh[7][p], an);
            an = h2fma(v2, tvh[8][p], an);
            const h2 ns = h2relu(sn + an);
            const h2 nd = h2relu(sn - an);
            accn[p] = h2fma(w2n, ns + nd, accn[p]);
        }
    }

    // ---- phase 3 (f32): taus + Delta ----
    const float b2j = Wf[54], b2n2 = Wf[55];
    const float Cs = 1.0f / 0.7f;
    float d[6][4];
    #pragma unroll
    for (int k = 0; k < 4; ++k) {
        const int p = k >> 1;
        const float aj  = (k & 1) ? (float)accj[p].y  : (float)accj[p].x;
        const float ajf = (k & 1) ? (float)accjf[p].y : (float)accjf[p].x;
        const float an  = (k & 1) ? (float)accn[p].y  : (float)accn[p].x;

        const float rt7 = __builtin_amdgcn_rcpf(0.5f + __expf(aj + b2j));
        const float rt8 = __builtin_amdgcn_rcpf(0.5f + __expf(ajf + b2j));
        const float rt6 = __builtin_amdgcn_rcpf(0.5f + __expf(an + b2n2));
        const float rrho = __builtin_amdgcn_rcpf(tv[0][k]);

        const float jx = 0.5f * (tv[3][k] + tv[6][k]);
        const float jy = 0.5f * (tv[3][k] - tv[6][k]);
        const float m3 = 0.5f * (tv[4][k] + tv[7][k]);
        const float m5 = 0.5f * (tv[4][k] - tv[7][k]);
        const float m7 = 0.5f * (tv[5][k] + tv[8][k]);
        const float m8 = 0.5f * (tv[5][k] - tv[8][k]);
        const float m4 = tv[1][k], m6 = tv[2][k];

        d[0][k] = (m3 - jx * jx * rrho) * Cs;
        d[1][k] = (m4 - jx * jy * rrho) * Cs;
        d[2][k] = (m5 - jy * jy * rrho) * Cs;
        d[3][k] = m6 * rt6;
        d[4][k] = m7 * rt7;
        d[5][k] = m8 * rt8;
    }

    // ---- phase 4 (f32): out[r] = f[r] + sum_c Qn[r][c]*d[c]  (Qn = -Minv[:,3:]) ----
    #pragma unroll
    for (int r = 0; r < 9; ++r) {
        float o0 = fv[r][0], o1 = fv[r][1], o2 = fv[r][2], o3 = fv[r][3];
        #pragma unroll
        for (int c = 0; c < 6; ++c) {
            const float w = Wf[r * 6 + c];
            o0 = fmaf(w, d[c][0], o0);
            o1 = fmaf(w, d[c][1], o1);
            o2 = fmaf(w, d[c][2], o2);
            o3 = fmaf(w, d[c][3], o3);
        }
        *reinterpret_cast<float4*>(out + (size_t)r * n2 + base) = make_float4(o0, o1, o2, o3);
    }
}

__global__ __launch_bounds__(256) void mrt_main(
    const float* __restrict__ f, const float* __restrict__ W,
    float* __restrict__ out, int n2)
{
    const h2*    Wh = reinterpret_cast<const h2*>(W);
    const float* Wf = W + 528;

    long chunk = (long)blockIdx.x * 2048;
    if (chunk + 2048 > n2) chunk = n2 - 2048;
    const long b0 = chunk + threadIdx.x * 4;
    const long b1 = b0 + 1024;

    // issue ALL 18 loads up front: tile-1's loads hide under tile-0 compute
    float4 cur[9], nxt[9];
    #pragma unroll
    for (int i = 0; i < 9; ++i)
        cur[i] = *reinterpret_cast<const float4*>(f + (size_t)i * n2 + b0);
    #pragma unroll
    for (int i = 0; i < 9; ++i)
        nxt[i] = *reinterpret_cast<const float4*>(f + (size_t)i * n2 + b1);

    process_tile(cur, Wh, Wf, out, b0, n2);
    process_tile(nxt, Wh, Wf, out, b1, n2);
}

extern "C" void kernel_launch(void* const* d_in, const int* in_sizes, int n_in,
                              void* d_out, int out_size, void* d_ws, size_t ws_size,
                              hipStream_t stream) {
    const float* f    = (const float*)d_in[0];
    const float* j_w1 = (const float*)d_in[1];
    const float* j_b1 = (const float*)d_in[2];
    const float* j_w2 = (const float*)d_in[3];
    const float* j_b2 = (const float*)d_in[4];
    const float* n_w1 = (const float*)d_in[5];
    const float* n_b1 = (const float*)d_in[6];
    const float* n_w2 = (const float*)d_in[7];
    const float* n_b2 = (const float*)d_in[8];
    const float* Mg   = (const float*)d_in[9];
    const float* Minv = (const float*)d_in[10];
    float* out = (float*)d_out;
    float* ws  = (float*)d_ws;

    const int n2 = in_sizes[0] / 9;
    const int grid = (n2 + 2047) / 2048;   // 2048 pts per block (256 thr x 4 pts x 2 tiles)

    prep_kernel<<<1, 256, 0, stream>>>(j_w1, j_b1, j_w2, j_b2,
                                       n_w1, n_b1, n_w2, n_b2, Mg, Minv, ws);
    mrt_main<<<grid, 256, 0, stream>>>(f, ws, out, n2);
}